// Round 2
// baseline (2809.143 us; speedup 1.0000x reference)
//
#include <hip/hip_runtime.h>

// DegModel: kernel-prediction net (17x conv3x3 + 1x1 conv to 441 taps) +
// tap-normalized spatially-varying 21x21 downsample (stride 4, reflect pad).
//
// Round 2: full fp64 conv chain + fp64 taps/sums. Round-1 fp32 chain was
// 2.2% off at degenerate (tiny tap-sum) positions vs the np reference —
// the 1/s amplification demands the raw taps match to ~1e-9. fp64 weights
// are pre-converted into d_ws so the conv inner loop keeps wave-uniform
// scalar weight operands (1 v_fma_f64 per MAC, no per-lane cvt).
//
// Shapes: x (8,3,256,256), z (8,3,64,64), h (8,64,64,64), kernel (8,441,64,64)
// Outputs concatenated in d_out: out (8*3*64*64 = 98304) ++ kernel (14450688).

#define NB 8        // batch
#define NF 64       // features
#define SP 4096     // 64*64 spatial
#define K2 441      // 21*21 taps
#define RES_WSTRIDE (64*64*9)

// ---------------------------------------------------------------------------
__global__ void cvt_f32_to_f64(const float* __restrict__ src,
                               double* __restrict__ dst, int n)
{
    int i = blockIdx.x * blockDim.x + threadIdx.x;
    if (i < n) dst[i] = (double)src[i];
}

// ---------------------------------------------------------------------------
// conv3x3 fp64, SAME zero-pad, NCHW. Block: 256 thr = 16x16 spatial tile,
// 16 oc. Grid: 8 b * 16 tiles * 4 oc-groups = 512 blocks (2 blocks/CU).
// Weights (fp64, pre-converted) are wave-uniform -> scalar 64b loads;
// inner loop is pure v_fma_f64.
// ---------------------------------------------------------------------------
template<int CIN, int CCHUNK, bool RELU, bool RESADD, typename TIN>
__global__ __launch_bounds__(256, 2)
void conv3x3_kernel(const TIN* __restrict__ in, const double* __restrict__ wgt,
                    const double* __restrict__ bias, const double* __restrict__ res,
                    double* __restrict__ out)
{
    const int bid  = blockIdx.x;
    const int ocg  = bid & 3;
    const int tile = (bid >> 2) & 15;
    const int b    = bid >> 6;
    const int i0   = (tile >> 2) << 4;
    const int j0   = (tile & 3) << 4;
    const int tid  = threadIdx.x;
    const int ti   = tid >> 4, tj = tid & 15;
    const int ocBase = ocg * 16;

    __shared__ double s_in[CCHUNK][18][18];  // 18x18 = 16 tile + 1 halo each side

    double acc[16];
#pragma unroll
    for (int oc = 0; oc < 16; ++oc) acc[oc] = bias[ocBase + oc];

    for (int cb = 0; cb < CIN; cb += CCHUNK) {
        // stage input chunk (zero pad at image edges)
        for (int e = tid; e < CCHUNK * 324; e += 256) {
            int c   = e / 324;
            int rem = e - c * 324;
            int r   = rem / 18;
            int cc  = rem - r * 18;
            int gr  = i0 + r - 1;
            int gc  = j0 + cc - 1;
            double v = 0.0;
            if (gr >= 0 && gr < 64 && gc >= 0 && gc < 64)
                v = (double)in[((b * CIN + cb + c) * 64 + gr) * 64 + gc];
            s_in[c][r][cc] = v;
        }
        __syncthreads();

        for (int c = 0; c < CCHUNK; ++c) {
            double v[9];
#pragma unroll
            for (int dy = 0; dy < 3; ++dy)
#pragma unroll
                for (int dx = 0; dx < 3; ++dx)
                    v[dy * 3 + dx] = s_in[c][ti + dy][tj + dx];
#pragma unroll
            for (int oc = 0; oc < 16; ++oc) {
                const double* wp = wgt + ((ocBase + oc) * CIN + cb + c) * 9;
                double a = acc[oc];
#pragma unroll
                for (int k = 0; k < 9; ++k) a = fma(wp[k], v[k], a);
                acc[oc] = a;
            }
        }
        __syncthreads();
    }

    const int pi = i0 + ti, pj = j0 + tj;
#pragma unroll
    for (int oc = 0; oc < 16; ++oc) {
        int idx = ((b * NF + ocBase + oc) * 64 + pi) * 64 + pj;
        double val = acc[oc];
        if (RELU)   val = fmax(val, 0.0);
        if (RESADD) val += res[idx];
        out[idx] = val;
    }
}

// ---------------------------------------------------------------------------
// 1x1 conv h(64ch, fp64) -> 441 taps fp64; raw taps rounded to fp32 into the
// kernel-output region of d_out; per-thread fp64 group tap-sum (oc-seq) to ws.
// Grid: 8 b * 16 pos-tiles(256 pos) * 4 oc-groups = 512 blocks.
// ---------------------------------------------------------------------------
__global__ __launch_bounds__(256)
void lastconv_kernel(const double* __restrict__ h, const double* __restrict__ wgt,
                     const double* __restrict__ bias, float* __restrict__ kraw,
                     double* __restrict__ sums)
{
    const int bid  = blockIdx.x;
    const int g    = bid & 3;
    const int tile = (bid >> 2) & 15;
    const int b    = bid >> 6;
    const int p    = tile * 256 + threadIdx.x;

    double hv[64];
#pragma unroll
    for (int c = 0; c < 64; ++c) hv[c] = h[(b * NF + c) * SP + p];

    const int oc0 = g * 111;
    const int oc1 = (oc0 + 111 < K2) ? oc0 + 111 : K2;   // 111,111,111,108
    double s = 0.0;
    for (int oc = oc0; oc < oc1; ++oc) {
        const double* wp = wgt + oc * 64;
        double k = bias[oc];
#pragma unroll
        for (int c = 0; c < 64; ++c) k = fma(wp[c], hv[c], k);
        kraw[(b * K2 + oc) * SP + p] = (float)k;
        s += k;
    }
    sums[(g * NB + b) * SP + p] = s;
}

// ---------------------------------------------------------------------------
// Normalize kernel in place + apply to reflect-padded 21x21 patches of x.
// Block: 256 thr = 16x16 output tile; x tile (81 rows x 84 cols x 3ch) staged
// in LDS with column swizzle v' = (v%4)*21 + v/4 so the stride-4 patch read
// becomes lane-stride-1 (row stride 84 -> exact 2-way bank alias = free).
// Grid: 8 b * 16 tiles * 4 tap-groups = 512; out accumulated via atomicAdd.
// Numerics: errors here are NOT 1/s-amplified (numerator-only), fp32 ok.
// ---------------------------------------------------------------------------
__global__ __launch_bounds__(256)
void apply_kernel(const float* __restrict__ x, const double* __restrict__ sums,
                  float* __restrict__ kout, float* __restrict__ out)
{
    const int bid  = blockIdx.x;
    const int g    = bid & 3;
    const int tile = (bid >> 2) & 15;
    const int b    = bid >> 6;
    const int i0   = (tile >> 2) << 4;
    const int j0   = (tile & 3) << 4;
    const int tid  = threadIdx.x;
    const int ti   = tid >> 4, tj = tid & 15;

    __shared__ float s_x[3][81][84];   // 81,648 B

    for (int e = tid; e < 3 * 81 * 84; e += 256) {
        int c   = e / 6804;
        int rem = e - c * 6804;
        int u   = rem / 84;
        int v   = rem - u * 84;
        int gr  = i0 * 4 + u - 10;
        int gc  = j0 * 4 + v - 10;
        gr = gr < 0 ? -gr : (gr > 255 ? 510 - gr : gr);
        gc = gc < 0 ? -gc : (gc > 255 ? 510 - gc : gc);
        int vp = (v & 3) * 21 + (v >> 2);
        s_x[c][u][vp] = x[((b * 3 + c) * 256 + gr) * 256 + gc];
    }
    __syncthreads();

    const int p = (i0 + ti) * 64 + (j0 + tj);
    double stot = 0.0;
#pragma unroll
    for (int gg = 0; gg < 4; ++gg) stot += sums[(gg * NB + b) * SP + p];
    const double inv = 1.0 / (stot + 1e-8);

    float o0 = 0.f, o1 = 0.f, o2 = 0.f;
    const int t0 = g * 111;
    const int t1 = (t0 + 111 < K2) ? t0 + 111 : K2;
    for (int t = t0; t < t1; ++t) {
        int ty = t / 21, tx = t - ty * 21;
        float* kp = &kout[(b * K2 + t) * SP + p];
        float k  = *kp;
        float kn = (float)((double)k * inv);
        *kp = kn;
        int u  = ti * 4 + ty;
        int vp = (tx & 3) * 21 + tj + (tx >> 2);
        o0 = fmaf(s_x[0][u][vp], kn, o0);
        o1 = fmaf(s_x[1][u][vp], kn, o1);
        o2 = fmaf(s_x[2][u][vp], kn, o2);
    }
    atomicAdd(&out[(b * 3 + 0) * SP + p], o0);
    atomicAdd(&out[(b * 3 + 1) * SP + p], o1);
    atomicAdd(&out[(b * 3 + 2) * SP + p], o2);
}

// ---------------------------------------------------------------------------
extern "C" void kernel_launch(void* const* d_in, const int* in_sizes, int n_in,
                              void* d_out, int out_size, void* d_ws, size_t ws_size,
                              hipStream_t stream)
{
    (void)in_sizes; (void)n_in; (void)out_size; (void)ws_size;

    const float* x       = (const float*)d_in[0];
    const float* z       = (const float*)d_in[1];

    float* out  = (float*)d_out;                 // (8,3,64,64)
    float* kout = (float*)d_out + NB * 3 * SP;   // (8,441,64,64) raw -> normalized

    // ws layout (doubles): converted weights | h | t (sums alias t)
    double* wd = (double*)d_ws;
    const int n_c0w = NF * 3 * 9;          // 1728
    const int n_c0b = NF;                  // 64
    const int n_rw  = 8 * NF * NF * 9;     // 294912
    const int n_rb  = 8 * NF;              // 512
    const int n_lw  = K2 * NF;             // 28224
    const int n_lb  = K2;                  // 441

    double* c0w = wd;
    double* c0b = c0w + n_c0w;
    double* rw1 = c0b + n_c0b;
    double* rb1 = rw1 + n_rw;
    double* rw2 = rb1 + n_rb;
    double* rb2 = rw2 + n_rw;
    double* lw  = rb2 + n_rb;
    double* lb  = lw  + n_lw;
    double* h   = lb  + n_lb + 7;          // ~4.97 MB of weights before this
    double* t   = h + NB * NF * SP;        // 16.8 MB each
    double* sums = t;                      // aliases t (free after conv chain)

    // convert all weights/biases to fp64 in ws
    {
        const float* srcs[8] = {(const float*)d_in[2], (const float*)d_in[3],
                                (const float*)d_in[4], (const float*)d_in[5],
                                (const float*)d_in[6], (const float*)d_in[7],
                                (const float*)d_in[8], (const float*)d_in[9]};
        double* dsts[8] = {c0w, c0b, rw1, rb1, rw2, rb2, lw, lb};
        const int ns[8] = {n_c0w, n_c0b, n_rw, n_rb, n_rw, n_rb, n_lw, n_lb};
        for (int i = 0; i < 8; ++i)
            cvt_f32_to_f64<<<(ns[i] + 255) / 256, 256, 0, stream>>>(srcs[i], dsts[i], ns[i]);
    }

    hipMemsetAsync(out, 0, NB * 3 * SP * sizeof(float), stream);

    conv3x3_kernel<3, 3, false, false, float><<<512, 256, 0, stream>>>(z, c0w, c0b, nullptr, h);
    for (int i = 0; i < 8; ++i) {
        conv3x3_kernel<64, 16, true,  false, double><<<512, 256, 0, stream>>>(
            h, rw1 + i * RES_WSTRIDE, rb1 + i * 64, nullptr, t);
        conv3x3_kernel<64, 16, false, true,  double><<<512, 256, 0, stream>>>(
            t, rw2 + i * RES_WSTRIDE, rb2 + i * 64, h, h);
    }
    lastconv_kernel<<<512, 256, 0, stream>>>(h, lw, lb, kout, sums);
    apply_kernel<<<512, 256, 0, stream>>>(x, sums, kout, out);
}